// Round 1
// baseline (187.286 us; speedup 1.0000x reference)
//
#include <hip/hip_runtime.h>
#include <math.h>

#define B_  4
#define S_  2048
#define H_  16
#define DK_ 8
#define E_  128

// ---------------------------------------------------------------------------
// Kernel 1: fused quantum projection + self-attention.
// One block per (q-row-chunk, b*h). Stages K=V=Q = cos(x+theta) (2048x8 fp32,
// 64KB) in LDS, then each thread computes 2 q-rows with single-pass
// exp-weighted accumulation (scores bounded by sqrt(8) -> no max tracking).
// ---------------------------------------------------------------------------
__global__ __launch_bounds__(256, 2)
void qattn_kernel(const float* __restrict__ x, const float* __restrict__ theta,
                  float* __restrict__ merged) {
    __shared__ float kl[S_ * DK_];              // 64 KB
    const int tid = threadIdx.x;
    const int bh  = blockIdx.y;
    const int b   = bh >> 4;                    // / H_
    const int h   = bh & 15;

    float th[DK_];
#pragma unroll
    for (int d = 0; d < DK_; ++d) th[d] = theta[d];

    // stage cos(x + theta) for the whole (b,h) slice
    const float* xb = x + ((size_t)b * S_) * E_ + h * DK_;
    for (int i = tid; i < S_; i += 256) {
        const float* xr = xb + (size_t)i * E_;
        float4 v0 = *(const float4*)(xr);
        float4 v1 = *(const float4*)(xr + 4);
        float c0 = __cosf(v0.x + th[0]);
        float c1 = __cosf(v0.y + th[1]);
        float c2 = __cosf(v0.z + th[2]);
        float c3 = __cosf(v0.w + th[3]);
        float c4 = __cosf(v1.x + th[4]);
        float c5 = __cosf(v1.y + th[5]);
        float c6 = __cosf(v1.z + th[6]);
        float c7 = __cosf(v1.w + th[7]);
        float4* kr = (float4*)&kl[i * DK_];
        kr[0] = make_float4(c0, c1, c2, c3);
        kr[1] = make_float4(c4, c5, c6, c7);
    }
    __syncthreads();

    // two q-rows per thread: r1 in [0,1024), r2 = r1 + 1024
    const int r1 = blockIdx.x * 256 + tid;      // gridDim.x == 4
    const int r2 = r1 + (S_ / 2);
    const float sc = 0.35355339059327373f;      // 1/sqrt(8), folded into q

    float p1[DK_], p2[DK_];
#pragma unroll
    for (int d = 0; d < DK_; ++d) p1[d] = kl[r1 * DK_ + d] * sc;
#pragma unroll
    for (int d = 0; d < DK_; ++d) p2[d] = kl[r2 * DK_ + d] * sc;

    float acc1[DK_] = {0,0,0,0,0,0,0,0};
    float acc2[DK_] = {0,0,0,0,0,0,0,0};
    float den1 = 0.f, den2 = 0.f;

    for (int j = 0; j < S_; j += 2) {
        float kA[DK_], kB[DK_];
        *(float4*)&kA[0] = *(const float4*)&kl[j * DK_];
        *(float4*)&kA[4] = *(const float4*)&kl[j * DK_ + 4];
        *(float4*)&kB[0] = *(const float4*)&kl[j * DK_ + 8];
        *(float4*)&kB[4] = *(const float4*)&kl[j * DK_ + 12];

        // pairwise trees keep the fma chains shallow
        float s1A = ((p1[0]*kA[0] + p1[1]*kA[1]) + (p1[2]*kA[2] + p1[3]*kA[3]))
                  + ((p1[4]*kA[4] + p1[5]*kA[5]) + (p1[6]*kA[6] + p1[7]*kA[7]));
        float s2A = ((p2[0]*kA[0] + p2[1]*kA[1]) + (p2[2]*kA[2] + p2[3]*kA[3]))
                  + ((p2[4]*kA[4] + p2[5]*kA[5]) + (p2[6]*kA[6] + p2[7]*kA[7]));
        float s1B = ((p1[0]*kB[0] + p1[1]*kB[1]) + (p1[2]*kB[2] + p1[3]*kB[3]))
                  + ((p1[4]*kB[4] + p1[5]*kB[5]) + (p1[6]*kB[6] + p1[7]*kB[7]));
        float s2B = ((p2[0]*kB[0] + p2[1]*kB[1]) + (p2[2]*kB[2] + p2[3]*kB[3]))
                  + ((p2[4]*kB[4] + p2[5]*kB[5]) + (p2[6]*kB[6] + p2[7]*kB[7]));

        float w1A = __expf(s1A);
        float w2A = __expf(s2A);
        float w1B = __expf(s1B);
        float w2B = __expf(s2B);
        den1 += w1A; den1 += w1B;
        den2 += w2A; den2 += w2B;
#pragma unroll
        for (int d = 0; d < DK_; ++d) {
            acc1[d] += w1A * kA[d];
            acc2[d] += w2A * kA[d];
        }
#pragma unroll
        for (int d = 0; d < DK_; ++d) {
            acc1[d] += w1B * kB[d];
            acc2[d] += w2B * kB[d];
        }
    }

    const float inv1 = 1.0f / den1;
    const float inv2 = 1.0f / den2;
    float* o1 = merged + ((size_t)(b * S_ + r1)) * E_ + h * DK_;
    float* o2 = merged + ((size_t)(b * S_ + r2)) * E_ + h * DK_;
    *(float4*)(o1)     = make_float4(acc1[0]*inv1, acc1[1]*inv1, acc1[2]*inv1, acc1[3]*inv1);
    *(float4*)(o1 + 4) = make_float4(acc1[4]*inv1, acc1[5]*inv1, acc1[6]*inv1, acc1[7]*inv1);
    *(float4*)(o2)     = make_float4(acc2[0]*inv2, acc2[1]*inv2, acc2[2]*inv2, acc2[3]*inv2);
    *(float4*)(o2 + 4) = make_float4(acc2[4]*inv2, acc2[5]*inv2, acc2[6]*inv2, acc2[7]*inv2);
}

// ---------------------------------------------------------------------------
// Kernel 2: in-place output projection  io[r][:] = io[r][:] @ Wc^T + bc.
// One block per 32 rows (owns whole rows -> in-place safe with one barrier).
// Wc staged in exactly 64KB LDS with XOR swizzle (4-way max bank conflict).
// ---------------------------------------------------------------------------
__global__ __launch_bounds__(256, 2)
void proj_kernel(const float* __restrict__ Wc, const float* __restrict__ bc,
                 float* __restrict__ io) {
    __shared__ float wc[E_ * E_];               // 64 KB, row-swizzled
    const int tid = threadIdx.x;
    const int r0  = blockIdx.x * 32;

    for (int idx = tid; idx < (E_ * E_) / 4; idx += 256) {
        int e  = idx >> 5;                      // 32 float4 per row
        int k4 = (idx & 31) * 4;
        float4 v = *(const float4*)&Wc[e * E_ + k4];
        int ks = k4 ^ ((e & 7) << 2);           // G4 XOR swizzle, 16B groups
        *(float4*)&wc[e * E_ + ks] = v;
    }
    __syncthreads();

    const int ty = tid >> 5;                    // 0..7  -> rows ty + 8i
    const int tx = tid & 31;                    // 0..31 -> cols tx + 32j

    float acc[4][4];
#pragma unroll
    for (int i = 0; i < 4; ++i)
#pragma unroll
        for (int jj = 0; jj < 4; ++jj) acc[i][jj] = 0.f;

    const float* arow0 = io + (size_t)(r0 + ty) * E_;
    for (int k = 0; k < E_; k += 4) {
        float4 a[4];
#pragma unroll
        for (int i = 0; i < 4; ++i)
            a[i] = *(const float4*)(arow0 + (size_t)(8 * i) * E_ + k);
        float4 bv[4];
#pragma unroll
        for (int jj = 0; jj < 4; ++jj) {
            int e  = tx + 32 * jj;
            int ks = k ^ ((e & 7) << 2);
            bv[jj] = *(const float4*)&wc[e * E_ + ks];
        }
#pragma unroll
        for (int i = 0; i < 4; ++i)
#pragma unroll
            for (int jj = 0; jj < 4; ++jj)
                acc[i][jj] += (a[i].x * bv[jj].x + a[i].y * bv[jj].y)
                            + (a[i].z * bv[jj].z + a[i].w * bv[jj].w);
    }

    float bias[4];
#pragma unroll
    for (int jj = 0; jj < 4; ++jj) bias[jj] = bc[tx + 32 * jj];

    __syncthreads();                            // all in-place reads done

#pragma unroll
    for (int i = 0; i < 4; ++i) {
        float* orow = io + (size_t)(r0 + ty + 8 * i) * E_;
#pragma unroll
        for (int jj = 0; jj < 4; ++jj)
            orow[tx + 32 * jj] = acc[i][jj] + bias[jj];
    }
}

extern "C" void kernel_launch(void* const* d_in, const int* in_sizes, int n_in,
                              void* d_out, int out_size, void* d_ws, size_t ws_size,
                              hipStream_t stream) {
    const float* x     = (const float*)d_in[0];   // (4, 2048, 128)
    const float* theta = (const float*)d_in[1];   // (8,)
    const float* Wc    = (const float*)d_in[2];   // (128, 128)
    const float* bc    = (const float*)d_in[3];   // (128,)
    float* out = (float*)d_out;                   // (4, 2048, 128)

    qattn_kernel<<<dim3(S_ / 512, B_ * H_), 256, 0, stream>>>(x, theta, out);
    proj_kernel<<<dim3((B_ * S_) / 32), 256, 0, stream>>>(Wc, bc, out);
}

// Round 3
// 105.424 us; speedup vs baseline: 1.7765x; 1.7765x over previous
//
#include <hip/hip_runtime.h>
#include <math.h>

#define B_  4
#define S_  2048
#define H_  16
#define DK_ 8
#define E_  128

typedef _Float16 f16x8  __attribute__((ext_vector_type(8)));
typedef __fp16   h2     __attribute__((ext_vector_type(2)));
typedef float    f32x16 __attribute__((ext_vector_type(16)));

union U4  { unsigned u[4]; f16x8 v; uint4 q; };
union H2U { h2 h; unsigned u; };

// log2(e)/sqrt(8): folds the 1/sqrt(dk) softmax scale and the exp->exp2 conversion
#define KSC 0.51006972f

// ---------------------------------------------------------------------------
// Fused quantum projection + attention, MFMA path.
// Block = 256 thr (4 waves), one (b,h) slice per blockIdx.y, 128 q-rows per
// block (32 per wave). LDS: K rows [2048][8] f16 (32KB) + V^T [10][2056] f16
// (row 8 = ones -> denominator, row 9 = zeros for clamped lanes). Staged once,
// then a barrier-free main loop: per 32-key tile one swapped QK^T mfma
// (32x32x16_f16, dims 8..15 and lanes 32..63 zero), exp in-register, one
// shfl_xor(32) half-exchange to build the PV A-fragment, two PV mfmas.
// ---------------------------------------------------------------------------
__global__ __launch_bounds__(256, 2)
void qattn_mfma(const float* __restrict__ x, const float* __restrict__ theta,
                float* __restrict__ out) {
    constexpr int VST = 2056;                       // V^T row stride (bank-spread, 16B aligned)
    __shared__ __align__(16) _Float16 smem[S_ * DK_ + 10 * VST];
    _Float16* Klds = smem;                          // [2048][8]
    _Float16* Vt   = smem + S_ * DK_;               // [10][VST]

    const int tid  = threadIdx.x;
    const int lane = tid & 63;
    const int wv   = tid >> 6;
    const int bh   = blockIdx.y;
    const int b    = bh >> 4;
    const int h    = bh & 15;

    float th[DK_];
#pragma unroll
    for (int d = 0; d < DK_; ++d) th[d] = theta[d];

    // ---- stage cos(x+theta): K row-major + V^T (pairs of keys) ----
    const float* xp = x + ((size_t)b * S_) * E_ + h * DK_;
#pragma unroll
    for (int m = 0; m < 4; ++m) {
        const int s0 = tid * 8 + 2 * m;
        float4 a0 = *(const float4*)(xp + (size_t)s0 * E_);
        float4 a1 = *(const float4*)(xp + (size_t)s0 * E_ + 4);
        float4 b0 = *(const float4*)(xp + (size_t)(s0 + 1) * E_);
        float4 b1 = *(const float4*)(xp + (size_t)(s0 + 1) * E_ + 4);
        float ca[8], cb[8];
        ca[0]=__cosf(a0.x+th[0]); ca[1]=__cosf(a0.y+th[1]); ca[2]=__cosf(a0.z+th[2]); ca[3]=__cosf(a0.w+th[3]);
        ca[4]=__cosf(a1.x+th[4]); ca[5]=__cosf(a1.y+th[5]); ca[6]=__cosf(a1.z+th[6]); ca[7]=__cosf(a1.w+th[7]);
        cb[0]=__cosf(b0.x+th[0]); cb[1]=__cosf(b0.y+th[1]); cb[2]=__cosf(b0.z+th[2]); cb[3]=__cosf(b0.w+th[3]);
        cb[4]=__cosf(b1.x+th[4]); cb[5]=__cosf(b1.y+th[5]); cb[6]=__cosf(b1.z+th[6]); cb[7]=__cosf(b1.w+th[7]);

        H2U p0, p1, p2, p3;
        p0.h = __builtin_amdgcn_cvt_pkrtz(ca[0], ca[1]);
        p1.h = __builtin_amdgcn_cvt_pkrtz(ca[2], ca[3]);
        p2.h = __builtin_amdgcn_cvt_pkrtz(ca[4], ca[5]);
        p3.h = __builtin_amdgcn_cvt_pkrtz(ca[6], ca[7]);
        uint4 ka = make_uint4(p0.u, p1.u, p2.u, p3.u);
        *(uint4*)&Klds[(size_t)s0 * DK_] = ka;
        p0.h = __builtin_amdgcn_cvt_pkrtz(cb[0], cb[1]);
        p1.h = __builtin_amdgcn_cvt_pkrtz(cb[2], cb[3]);
        p2.h = __builtin_amdgcn_cvt_pkrtz(cb[4], cb[5]);
        p3.h = __builtin_amdgcn_cvt_pkrtz(cb[6], cb[7]);
        uint4 kb = make_uint4(p0.u, p1.u, p2.u, p3.u);
        *(uint4*)&Klds[(size_t)(s0 + 1) * DK_] = kb;

#pragma unroll
        for (int d = 0; d < DK_; ++d) {             // V^T: (key s0, s0+1) pair
            H2U tv; tv.h = __builtin_amdgcn_cvt_pkrtz(ca[d], cb[d]);
            *(unsigned*)&Vt[d * VST + s0] = tv.u;
        }
        *(unsigned*)&Vt[8 * VST + s0] = 0x3C003C00u;  // ones row -> denominator
        *(unsigned*)&Vt[9 * VST + s0] = 0u;           // zero row for clamped lanes
    }
    __syncthreads();

    // ---- per-wave 32 q-rows over all 2048 keys ----
    const int  qrow0 = blockIdx.x * 128 + wv * 32;
    const int  l31   = lane & 31;
    const int  hi    = lane >> 5;
    const bool lo32  = (lane < 32);

    f16x8 qf = {};                                  // Q^T B-frag: lanes>=32 zero (dims 8..15)
    if (lo32) qf = *(const f16x8*)&Klds[(size_t)(qrow0 + l31) * DK_];

    const f32x16 z16 = {};                          // constant zero C operand
    f32x16 accO = {};                               // O accumulator (col = lane&31)

    const int nc = (l31 <= 8) ? l31 : 9;            // clamp unused cols to zero row
    const _Float16* vbase = &Vt[nc * VST + hi * 8];

    f16x8 kf = {};                                  // K A-frag: lanes>=32 zero

    for (int kt = 0; kt < S_ / 32; ++kt) {
        if (lo32) kf = *(const f16x8*)&Klds[(size_t)(kt * 32 + l31) * DK_];
        // S^T[key][qrow] for 32 keys x 32 qrows; lane holds 16 keys of qrow=lane&31
        f32x16 sc = __builtin_amdgcn_mfma_f32_32x32x16_f16(kf, qf, z16, 0, 0, 0);

        unsigned X[4][2];                           // X[q] = f16 pair-packed exp(scores)
#pragma unroll
        for (int q = 0; q < 4; ++q) {
            float w0 = exp2f(sc[4 * q + 0] * KSC);
            float w1 = exp2f(sc[4 * q + 1] * KSC);
            float w2 = exp2f(sc[4 * q + 2] * KSC);
            float w3 = exp2f(sc[4 * q + 3] * KSC);
            H2U p0, p1;
            p0.h = __builtin_amdgcn_cvt_pkrtz(w0, w1);
            p1.h = __builtin_amdgcn_cvt_pkrtz(w2, w3);
            X[q][0] = p0.u; X[q][1] = p1.u;
        }

#pragma unroll
        for (int s = 0; s < 2; ++s) {               // two PV steps of 16 keys
            U4 pa;
#pragma unroll
            for (int i = 0; i < 2; ++i) {
                unsigned mine_lo = X[2 * s][i];     // q = 2s   (dest hi=0 wants this)
                unsigned mine_hi = X[2 * s + 1][i]; // q = 2s+1 (dest hi=1 wants this)
                unsigned payload = lo32 ? mine_hi : mine_lo;
                unsigned recv = (unsigned)__shfl_xor((int)payload, 32, 64);
                pa.u[i]     = lo32 ? mine_lo : recv;   // keys j=0..3 (from hi=0 half)
                pa.u[2 + i] = lo32 ? recv : mine_hi;   // keys j=4..7 (from hi=1 half)
            }
            f16x8 vf = *(const f16x8*)(vbase + kt * 32 + s * 16);
            accO = __builtin_amdgcn_mfma_f32_32x32x16_f16(pa.v, vf, accO, 0, 0, 0);
        }
    }

    // ---- epilogue: normalize by col-8 (ones column) and store ----
    const int n = l31;
    float* obase = out + ((size_t)(b * S_ + qrow0)) * E_ + h * DK_ + n;
#pragma unroll
    for (int i = 0; i < 16; ++i) {
        float den = __shfl(accO[i], (lane & 32) | 8, 64);
        float val = accO[i] / den;
        int row = (i & 3) + 8 * (i >> 2) + 4 * hi;
        if (n < DK_) obase[(size_t)row * E_] = val;
    }
}

// ---------------------------------------------------------------------------
// In-place output projection  io[r][:] = io[r][:] @ Wc^T + bc   (unchanged)
// ---------------------------------------------------------------------------
__global__ __launch_bounds__(256, 2)
void proj_kernel(const float* __restrict__ Wc, const float* __restrict__ bc,
                 float* __restrict__ io) {
    __shared__ float wc[E_ * E_];
    const int tid = threadIdx.x;
    const int r0  = blockIdx.x * 32;

    for (int idx = tid; idx < (E_ * E_) / 4; idx += 256) {
        int e  = idx >> 5;
        int k4 = (idx & 31) * 4;
        float4 v = *(const float4*)&Wc[e * E_ + k4];
        int ks = k4 ^ ((e & 7) << 2);
        *(float4*)&wc[e * E_ + ks] = v;
    }
    __syncthreads();

    const int ty = tid >> 5;
    const int tx = tid & 31;

    float acc[4][4];
#pragma unroll
    for (int i = 0; i < 4; ++i)
#pragma unroll
        for (int jj = 0; jj < 4; ++jj) acc[i][jj] = 0.f;

    const float* arow0 = io + (size_t)(r0 + ty) * E_;
    for (int k = 0; k < E_; k += 4) {
        float4 a[4];
#pragma unroll
        for (int i = 0; i < 4; ++i)
            a[i] = *(const float4*)(arow0 + (size_t)(8 * i) * E_ + k);
        float4 bv[4];
#pragma unroll
        for (int jj = 0; jj < 4; ++jj) {
            int e  = tx + 32 * jj;
            int ks = k ^ ((e & 7) << 2);
            bv[jj] = *(const float4*)&wc[e * E_ + ks];
        }
#pragma unroll
        for (int i = 0; i < 4; ++i)
#pragma unroll
            for (int jj = 0; jj < 4; ++jj)
                acc[i][jj] += (a[i].x * bv[jj].x + a[i].y * bv[jj].y)
                            + (a[i].z * bv[jj].z + a[i].w * bv[jj].w);
    }

    float bias[4];
#pragma unroll
    for (int jj = 0; jj < 4; ++jj) bias[jj] = bc[tx + 32 * jj];

    __syncthreads();

#pragma unroll
    for (int i = 0; i < 4; ++i) {
        float* orow = io + (size_t)(r0 + ty + 8 * i) * E_;
#pragma unroll
        for (int jj = 0; jj < 4; ++jj)
            orow[tx + 32 * jj] = acc[i][jj] + bias[jj];
    }
}

extern "C" void kernel_launch(void* const* d_in, const int* in_sizes, int n_in,
                              void* d_out, int out_size, void* d_ws, size_t ws_size,
                              hipStream_t stream) {
    const float* x     = (const float*)d_in[0];   // (4, 2048, 128)
    const float* theta = (const float*)d_in[1];   // (8,)
    const float* Wc    = (const float*)d_in[2];   // (128, 128)
    const float* bc    = (const float*)d_in[3];   // (128,)
    float* out = (float*)d_out;                   // (4, 2048, 128)

    qattn_mfma<<<dim3(S_ / 128, B_ * H_), 256, 0, stream>>>(x, theta, out);
    proj_kernel<<<dim3((B_ * S_) / 32), 256, 0, stream>>>(Wc, bc, out);
}

// Round 4
// 55.777 us; speedup vs baseline: 3.3578x; 1.8901x over previous
//
#include <hip/hip_runtime.h>
#include <math.h>

#define B_  4
#define S_  2048
#define H_  16
#define DK_ 8
#define E_  128

typedef _Float16 f16x8  __attribute__((ext_vector_type(8)));
typedef __fp16   h2     __attribute__((ext_vector_type(2)));
typedef float    f32x16 __attribute__((ext_vector_type(16)));
typedef int      i32x2  __attribute__((ext_vector_type(2)));

union U4  { unsigned u[4]; f16x8 v; uint4 q; };
union H2U { h2 h; unsigned u; };

// log2(e)/sqrt(8): folds the 1/sqrt(dk) softmax scale and the exp->exp2 conversion
#define KSC 0.51006972f

static __device__ __forceinline__ float fexp2(float x) {
#if __has_builtin(__builtin_amdgcn_exp2f)
    return __builtin_amdgcn_exp2f(x);          // bare v_exp_f32
#else
    return __builtin_exp2f(x);
#endif
}

static __device__ __forceinline__ float frcp(float x) {
#if __has_builtin(__builtin_amdgcn_rcpf)
    return __builtin_amdgcn_rcpf(x);
#else
    return 1.0f / x;
#endif
}

// ---------------------------------------------------------------------------
// Fused quantum projection + attention, MFMA path.
// Block = 512 thr (8 waves), one (b,h) slice per blockIdx.y, 256 q-rows per
// block (32 per wave). LDS: K rows [2048][8] f16 (32KB) + V^T [9][2056] f16
// (row 8 = ones -> denominator). Staged once, then a barrier-free main loop:
// per 32-key tile one swapped QK^T mfma (32x32x16_f16, scale pre-folded into
// the f16 Q fragment), bare v_exp_f32, cvt_pkrtz pack, v_permlane32_swap
// half-exchange to build the PV A-fragment, two PV mfmas.
// ---------------------------------------------------------------------------
__global__ __launch_bounds__(512, 4)
void qattn_mfma(const float* __restrict__ x, const float* __restrict__ theta,
                float* __restrict__ out) {
    constexpr int VST = 2056;                       // V^T row stride (bank-spread, 16B aligned)
    __shared__ __align__(16) _Float16 smem[S_ * DK_ + 9 * VST];
    _Float16* Klds = smem;                          // [2048][8]
    _Float16* Vt   = smem + S_ * DK_;               // [9][VST]

    const int tid  = threadIdx.x;
    const int lane = tid & 63;
    const int wv   = tid >> 6;
    const int bh   = blockIdx.y;
    const int b    = bh >> 4;
    const int h    = bh & 15;

    float th[DK_];
#pragma unroll
    for (int d = 0; d < DK_; ++d) th[d] = theta[d];

    // ---- stage cos(x+theta): K row-major + V^T (pairs of keys) ----
    const float* xp = x + ((size_t)b * S_) * E_ + h * DK_;
#pragma unroll
    for (int m = 0; m < 2; ++m) {
        const int s0 = tid * 4 + 2 * m;
        float4 a0 = *(const float4*)(xp + (size_t)s0 * E_);
        float4 a1 = *(const float4*)(xp + (size_t)s0 * E_ + 4);
        float4 b0 = *(const float4*)(xp + (size_t)(s0 + 1) * E_);
        float4 b1 = *(const float4*)(xp + (size_t)(s0 + 1) * E_ + 4);
        float ca[8], cb[8];
        ca[0]=__cosf(a0.x+th[0]); ca[1]=__cosf(a0.y+th[1]); ca[2]=__cosf(a0.z+th[2]); ca[3]=__cosf(a0.w+th[3]);
        ca[4]=__cosf(a1.x+th[4]); ca[5]=__cosf(a1.y+th[5]); ca[6]=__cosf(a1.z+th[6]); ca[7]=__cosf(a1.w+th[7]);
        cb[0]=__cosf(b0.x+th[0]); cb[1]=__cosf(b0.y+th[1]); cb[2]=__cosf(b0.z+th[2]); cb[3]=__cosf(b0.w+th[3]);
        cb[4]=__cosf(b1.x+th[4]); cb[5]=__cosf(b1.y+th[5]); cb[6]=__cosf(b1.z+th[6]); cb[7]=__cosf(b1.w+th[7]);

        H2U p0, p1, p2, p3;
        p0.h = __builtin_amdgcn_cvt_pkrtz(ca[0], ca[1]);
        p1.h = __builtin_amdgcn_cvt_pkrtz(ca[2], ca[3]);
        p2.h = __builtin_amdgcn_cvt_pkrtz(ca[4], ca[5]);
        p3.h = __builtin_amdgcn_cvt_pkrtz(ca[6], ca[7]);
        uint4 ka = make_uint4(p0.u, p1.u, p2.u, p3.u);
        *(uint4*)&Klds[(size_t)s0 * DK_] = ka;
        p0.h = __builtin_amdgcn_cvt_pkrtz(cb[0], cb[1]);
        p1.h = __builtin_amdgcn_cvt_pkrtz(cb[2], cb[3]);
        p2.h = __builtin_amdgcn_cvt_pkrtz(cb[4], cb[5]);
        p3.h = __builtin_amdgcn_cvt_pkrtz(cb[6], cb[7]);
        uint4 kb = make_uint4(p0.u, p1.u, p2.u, p3.u);
        *(uint4*)&Klds[(size_t)(s0 + 1) * DK_] = kb;

#pragma unroll
        for (int d = 0; d < DK_; ++d) {             // V^T: (key s0, s0+1) pair
            H2U tv; tv.h = __builtin_amdgcn_cvt_pkrtz(ca[d], cb[d]);
            *(unsigned*)&Vt[d * VST + s0] = tv.u;
        }
        *(unsigned*)&Vt[8 * VST + s0] = 0x3C003C00u;  // ones row -> denominator
    }
    __syncthreads();

    // ---- per-wave 32 q-rows over all 2048 keys ----
    const int  qrow0 = blockIdx.x * 256 + wv * 32;
    const int  l31   = lane & 31;
    const int  hi    = lane >> 5;
    const bool lo32  = (lane < 32);

    f16x8 qf = {};                                  // Q^T B-frag: lanes>=32 zero (dims 8..15)
    if (lo32) {
        qf = *(const f16x8*)&Klds[(size_t)(qrow0 + l31) * DK_];
#pragma unroll
        for (int d = 0; d < DK_; ++d)               // fold softmax scale + log2e into Q
            qf[d] = qf[d] * (_Float16)KSC;
    }

    const f32x16 z16 = {};                          // constant zero C operand
    f32x16 accO = {};                               // O accumulator (col = lane&31)

    const int nc = (l31 <= 8) ? l31 : 8;            // clamp unused cols to ones row
    const _Float16* vbase = &Vt[nc * VST + hi * 8];

    f16x8 kf = {};                                  // K A-frag: lanes>=32 zero

    for (int kt = 0; kt < S_ / 32; ++kt) {
        if (lo32) kf = *(const f16x8*)&Klds[(size_t)(kt * 32 + l31) * DK_];
        // S^T[key][qrow] for 32 keys x 32 qrows; lane holds 16 keys of qrow=lane&31
        f32x16 sc = __builtin_amdgcn_mfma_f32_32x32x16_f16(kf, qf, z16, 0, 0, 0);

        unsigned X[4][2];                           // X[q] = f16 pair-packed exp(scores)
#pragma unroll
        for (int q = 0; q < 4; ++q) {
            float w0 = fexp2(sc[4 * q + 0]);
            float w1 = fexp2(sc[4 * q + 1]);
            float w2 = fexp2(sc[4 * q + 2]);
            float w3 = fexp2(sc[4 * q + 3]);
            H2U p0, p1;
            p0.h = __builtin_amdgcn_cvt_pkrtz(w0, w1);
            p1.h = __builtin_amdgcn_cvt_pkrtz(w2, w3);
            X[q][0] = p0.u; X[q][1] = p1.u;
        }

#pragma unroll
        for (int s = 0; s < 2; ++s) {               // two PV steps of 16 keys
            U4 pa;
#pragma unroll
            for (int i = 0; i < 2; ++i) {
#if __has_builtin(__builtin_amdgcn_permlane32_swap)
                i32x2 r = __builtin_amdgcn_permlane32_swap(
                    (int)X[2 * s][i], (int)X[2 * s + 1][i], false, false);
                pa.u[i]     = (unsigned)r[0];       // keys j=0..3 (from hi=0 half)
                pa.u[2 + i] = (unsigned)r[1];       // keys j=4..7 (from hi=1 half)
#else
                unsigned mine_lo = X[2 * s][i];
                unsigned mine_hi = X[2 * s + 1][i];
                unsigned payload = lo32 ? mine_hi : mine_lo;
                unsigned recv = (unsigned)__shfl_xor((int)payload, 32, 64);
                pa.u[i]     = lo32 ? mine_lo : recv;
                pa.u[2 + i] = lo32 ? recv : mine_hi;
#endif
            }
            f16x8 vf = *(const f16x8*)(vbase + kt * 32 + s * 16);
            accO = __builtin_amdgcn_mfma_f32_32x32x16_f16(pa.v, vf, accO, 0, 0, 0);
        }
    }

    // ---- epilogue: normalize by col-8 (ones column) and store ----
    const int n = l31;
    float* obase = out + ((size_t)(b * S_ + qrow0)) * E_ + h * DK_ + n;
#pragma unroll
    for (int i = 0; i < 16; ++i) {
        float den = __shfl(accO[i], (lane & 32) | 8, 64);
        float val = accO[i] * frcp(den);
        int row = (i & 3) + 8 * (i >> 2) + 4 * hi;
        if (n < DK_) obase[(size_t)row * E_] = val;
    }
}

// ---------------------------------------------------------------------------
// In-place output projection  io[r][:] = io[r][:] @ Wc^T + bc   (unchanged)
// ---------------------------------------------------------------------------
__global__ __launch_bounds__(256, 2)
void proj_kernel(const float* __restrict__ Wc, const float* __restrict__ bc,
                 float* __restrict__ io) {
    __shared__ float wc[E_ * E_];
    const int tid = threadIdx.x;
    const int r0  = blockIdx.x * 32;

    for (int idx = tid; idx < (E_ * E_) / 4; idx += 256) {
        int e  = idx >> 5;
        int k4 = (idx & 31) * 4;
        float4 v = *(const float4*)&Wc[e * E_ + k4];
        int ks = k4 ^ ((e & 7) << 2);
        *(float4*)&wc[e * E_ + ks] = v;
    }
    __syncthreads();

    const int ty = tid >> 5;
    const int tx = tid & 31;

    float acc[4][4];
#pragma unroll
    for (int i = 0; i < 4; ++i)
#pragma unroll
        for (int jj = 0; jj < 4; ++jj) acc[i][jj] = 0.f;

    const float* arow0 = io + (size_t)(r0 + ty) * E_;
    for (int k = 0; k < E_; k += 4) {
        float4 a[4];
#pragma unroll
        for (int i = 0; i < 4; ++i)
            a[i] = *(const float4*)(arow0 + (size_t)(8 * i) * E_ + k);
        float4 bv[4];
#pragma unroll
        for (int jj = 0; jj < 4; ++jj) {
            int e  = tx + 32 * jj;
            int ks = k ^ ((e & 7) << 2);
            bv[jj] = *(const float4*)&wc[e * E_ + ks];
        }
#pragma unroll
        for (int i = 0; i < 4; ++i)
#pragma unroll
            for (int jj = 0; jj < 4; ++jj)
                acc[i][jj] += (a[i].x * bv[jj].x + a[i].y * bv[jj].y)
                            + (a[i].z * bv[jj].z + a[i].w * bv[jj].w);
    }

    float bias[4];
#pragma unroll
    for (int jj = 0; jj < 4; ++jj) bias[jj] = bc[tx + 32 * jj];

    __syncthreads();

#pragma unroll
    for (int i = 0; i < 4; ++i) {
        float* orow = io + (size_t)(r0 + ty + 8 * i) * E_;
#pragma unroll
        for (int jj = 0; jj < 4; ++jj)
            orow[tx + 32 * jj] = acc[i][jj] + bias[jj];
    }
}

extern "C" void kernel_launch(void* const* d_in, const int* in_sizes, int n_in,
                              void* d_out, int out_size, void* d_ws, size_t ws_size,
                              hipStream_t stream) {
    const float* x     = (const float*)d_in[0];   // (4, 2048, 128)
    const float* theta = (const float*)d_in[1];   // (8,)
    const float* Wc    = (const float*)d_in[2];   // (128, 128)
    const float* bc    = (const float*)d_in[3];   // (128,)
    float* out = (float*)d_out;                   // (4, 2048, 128)

    qattn_mfma<<<dim3(S_ / 256, B_ * H_), 512, 0, stream>>>(x, theta, out);
    proj_kernel<<<dim3((B_ * S_) / 32), 256, 0, stream>>>(Wc, bc, out);
}

// Round 5
// 47.776 us; speedup vs baseline: 3.9201x; 1.1675x over previous
//
#include <hip/hip_runtime.h>
#include <math.h>

#define B_  4
#define S_  2048
#define H_  16
#define DK_ 8
#define E_  128

typedef _Float16 f16x8  __attribute__((ext_vector_type(8)));
typedef __fp16   h2     __attribute__((ext_vector_type(2)));
typedef float    f32x16 __attribute__((ext_vector_type(16)));
typedef int      i32x2  __attribute__((ext_vector_type(2)));

union U4  { unsigned u[4]; f16x8 v; uint4 q; };
union H2U { h2 h; unsigned u; };

// log2(e)/sqrt(8): folds the 1/sqrt(dk) softmax scale and the exp->exp2 conversion
#define KSC 0.51006972f

static __device__ __forceinline__ float fexp2(float x) {
#if __has_builtin(__builtin_amdgcn_exp2f)
    return __builtin_amdgcn_exp2f(x);          // bare v_exp_f32
#else
    return __builtin_exp2f(x);
#endif
}

static __device__ __forceinline__ float frcp(float x) {
#if __has_builtin(__builtin_amdgcn_rcpf)
    return __builtin_amdgcn_rcpf(x);
#else
    return 1.0f / x;
#endif
}

// ---------------------------------------------------------------------------
// Fused quantum projection + attention, MFMA path, software-pipelined.
// Block = 512 thr (8 waves), one (b,h) slice per blockIdx.y, 256 q-rows per
// block (32 per wave). LDS: K rows [2048][8] f16 (32KB) + V^T [9][2056] f16
// (row 8 = ones -> denominator). Main loop is unroll-2 with rotating register
// prefetch: each LDS fragment load has a full tile of independent work to
// hide under (4 waves/SIMD can't hide the chain alone).
// ---------------------------------------------------------------------------
__global__ __launch_bounds__(512, 4)
void qattn_mfma(const float* __restrict__ x, const float* __restrict__ theta,
                float* __restrict__ out) {
    constexpr int VST = 2056;                       // V^T row stride (bank-spread, 16B aligned)
    __shared__ __align__(16) _Float16 smem[S_ * DK_ + 9 * VST];
    _Float16* Klds = smem;                          // [2048][8]
    _Float16* Vt   = smem + S_ * DK_;               // [9][VST]

    const int tid  = threadIdx.x;
    const int lane = tid & 63;
    const int wv   = tid >> 6;
    const int bh   = blockIdx.y;
    const int b    = bh >> 4;
    const int h    = bh & 15;

    float th[DK_];
#pragma unroll
    for (int d = 0; d < DK_; ++d) th[d] = theta[d];

    // ---- stage cos(x+theta): K row-major + V^T (pairs of keys) ----
    const float* xp = x + ((size_t)b * S_) * E_ + h * DK_;
#pragma unroll
    for (int m = 0; m < 2; ++m) {
        const int s0 = tid * 4 + 2 * m;
        float4 a0 = *(const float4*)(xp + (size_t)s0 * E_);
        float4 a1 = *(const float4*)(xp + (size_t)s0 * E_ + 4);
        float4 b0 = *(const float4*)(xp + (size_t)(s0 + 1) * E_);
        float4 b1 = *(const float4*)(xp + (size_t)(s0 + 1) * E_ + 4);
        float ca[8], cb[8];
        ca[0]=__cosf(a0.x+th[0]); ca[1]=__cosf(a0.y+th[1]); ca[2]=__cosf(a0.z+th[2]); ca[3]=__cosf(a0.w+th[3]);
        ca[4]=__cosf(a1.x+th[4]); ca[5]=__cosf(a1.y+th[5]); ca[6]=__cosf(a1.z+th[6]); ca[7]=__cosf(a1.w+th[7]);
        cb[0]=__cosf(b0.x+th[0]); cb[1]=__cosf(b0.y+th[1]); cb[2]=__cosf(b0.z+th[2]); cb[3]=__cosf(b0.w+th[3]);
        cb[4]=__cosf(b1.x+th[4]); cb[5]=__cosf(b1.y+th[5]); cb[6]=__cosf(b1.z+th[6]); cb[7]=__cosf(b1.w+th[7]);

        H2U p0, p1, p2, p3;
        p0.h = __builtin_amdgcn_cvt_pkrtz(ca[0], ca[1]);
        p1.h = __builtin_amdgcn_cvt_pkrtz(ca[2], ca[3]);
        p2.h = __builtin_amdgcn_cvt_pkrtz(ca[4], ca[5]);
        p3.h = __builtin_amdgcn_cvt_pkrtz(ca[6], ca[7]);
        *(uint4*)&Klds[(size_t)s0 * DK_] = make_uint4(p0.u, p1.u, p2.u, p3.u);
        p0.h = __builtin_amdgcn_cvt_pkrtz(cb[0], cb[1]);
        p1.h = __builtin_amdgcn_cvt_pkrtz(cb[2], cb[3]);
        p2.h = __builtin_amdgcn_cvt_pkrtz(cb[4], cb[5]);
        p3.h = __builtin_amdgcn_cvt_pkrtz(cb[6], cb[7]);
        *(uint4*)&Klds[(size_t)(s0 + 1) * DK_] = make_uint4(p0.u, p1.u, p2.u, p3.u);

#pragma unroll
        for (int d = 0; d < DK_; ++d) {             // V^T: (key s0, s0+1) pair
            H2U tv; tv.h = __builtin_amdgcn_cvt_pkrtz(ca[d], cb[d]);
            *(unsigned*)&Vt[d * VST + s0] = tv.u;
        }
        *(unsigned*)&Vt[8 * VST + s0] = 0x3C003C00u;  // ones row -> denominator
    }
    __syncthreads();

    // ---- per-wave 32 q-rows over all 2048 keys ----
    const int  qrow0 = blockIdx.x * 256 + wv * 32;
    const int  l31   = lane & 31;
    const int  hi    = lane >> 5;
    const bool lo32  = (lane < 32);

    f16x8 qf = {};                                  // Q^T B-frag: lanes>=32 zero (dims 8..15)
    if (lo32) {
        qf = *(const f16x8*)&Klds[(size_t)(qrow0 + l31) * DK_];
#pragma unroll
        for (int d = 0; d < DK_; ++d)               // fold softmax scale + log2e into Q
            qf[d] = qf[d] * (_Float16)KSC;
    }

    const f32x16 z16 = {};                          // constant zero C operand
    f32x16 accO = {};                               // O accumulator (col = lane&31)

    const int nc = (l31 <= 8) ? l31 : 8;            // clamp unused cols to ones row
    const _Float16* vbase = &Vt[nc * VST + hi * 8];

    // kf loads are unconditional: lanes>=32 duplicate their l31 partner's row;
    // their A-contribution hits qf's zeroed k=8..15 half -> 0.
#define LDK(T)    (*(const f16x8*)&Klds[(size_t)((((T) & 63) * 32) + l31) * DK_])
#define LDV(T, S) (*(const f16x8*)(vbase + (((T) & 63) * 32) + (S) * 16))

    f16x8 kfA  = LDK(0), kfB  = LDK(1);
    f16x8 vfA0 = LDV(0,0), vfA1 = LDV(0,1);
    f16x8 vfB0 = LDV(1,0), vfB1 = LDV(1,1);

#define TILE_BODY(KF, VF0, VF1, KTN)                                           \
    {                                                                          \
        f32x16 sc = __builtin_amdgcn_mfma_f32_32x32x16_f16(KF, qf, z16,0,0,0); \
        KF = LDK(KTN);                          /* refill after consume */     \
        unsigned X[4][2];                                                      \
        _Pragma("unroll")                                                      \
        for (int q = 0; q < 4; ++q) {                                          \
            float w0 = fexp2(sc[4*q+0]);                                       \
            float w1 = fexp2(sc[4*q+1]);                                       \
            float w2 = fexp2(sc[4*q+2]);                                       \
            float w3 = fexp2(sc[4*q+3]);                                       \
            H2U p0, p1;                                                        \
            p0.h = __builtin_amdgcn_cvt_pkrtz(w0, w1);                         \
            p1.h = __builtin_amdgcn_cvt_pkrtz(w2, w3);                         \
            X[q][0] = p0.u; X[q][1] = p1.u;                                    \
        }                                                                      \
        _Pragma("unroll")                                                      \
        for (int s = 0; s < 2; ++s) {                                          \
            U4 pa;                                                             \
            _Pragma("unroll")                                                  \
            for (int i = 0; i < 2; ++i) {                                      \
                i32x2 r = __builtin_amdgcn_permlane32_swap(                    \
                    (int)X[2*s][i], (int)X[2*s+1][i], false, false);           \
                pa.u[i]     = (unsigned)r[0];                                  \
                pa.u[2 + i] = (unsigned)r[1];                                  \
            }                                                                  \
            accO = __builtin_amdgcn_mfma_f32_32x32x16_f16(                     \
                pa.v, (s == 0) ? VF0 : VF1, accO, 0, 0, 0);                    \
        }                                                                      \
        VF0 = LDV(KTN, 0); VF1 = LDV(KTN, 1);   /* refill after consume */     \
    }

    for (int kt = 0; kt < S_ / 32; kt += 2) {
        TILE_BODY(kfA, vfA0, vfA1, kt + 2)
        TILE_BODY(kfB, vfB0, vfB1, kt + 3)
    }
#undef TILE_BODY
#undef LDK
#undef LDV

    // ---- epilogue: normalize by col-8 (ones column) and store ----
    const int n = l31;
    float* obase = out + ((size_t)(b * S_ + qrow0)) * E_ + h * DK_ + n;
#pragma unroll
    for (int i = 0; i < 16; ++i) {
        float den = __shfl(accO[i], (lane & 32) | 8, 64);
        float val = accO[i] * frcp(den);
        int row = (i & 3) + 8 * (i >> 2) + 4 * hi;
        if (n < DK_) obase[(size_t)row * E_] = val;
    }
}

// ---------------------------------------------------------------------------
// In-place output projection via f16 MFMA:  io[r][:] = io[r][:] @ Wc^T + bc.
// 128 blocks x 64 rows. A (64x128) and Wc (128x128) staged as f16 in 48KB LDS
// with 16B-chunk XOR swizzle; wave w owns row-group w&1, col-groups
// {2*(w>>1), 2*(w>>1)+1}; 8 K-steps of 32x32x16 mfma.
// ---------------------------------------------------------------------------
__global__ __launch_bounds__(256, 2)
void proj_mfma(const float* __restrict__ Wc, const float* __restrict__ bc,
               float* __restrict__ io) {
    __shared__ __align__(16) _Float16 As[64 * E_];   // 16KB
    __shared__ __align__(16) _Float16 Bs[E_ * E_];   // 32KB
    const int tid  = threadIdx.x;
    const int lane = tid & 63;
    const int wv   = tid >> 6;
    const int l31  = lane & 31;
    const int hi   = lane >> 5;
    const int r0   = blockIdx.x * 64;

    // stage A rows (io, fp32 -> f16) with chunk swizzle
    for (int i = tid; i < 64 * 16; i += 256) {
        int r = i >> 4, c = i & 15;
        const float* s = io + (size_t)(r0 + r) * E_ + c * 8;
        float4 a = *(const float4*)s;
        float4 b = *(const float4*)(s + 4);
        H2U p0, p1, p2, p3;
        p0.h = __builtin_amdgcn_cvt_pkrtz(a.x, a.y);
        p1.h = __builtin_amdgcn_cvt_pkrtz(a.z, a.w);
        p2.h = __builtin_amdgcn_cvt_pkrtz(b.x, b.y);
        p3.h = __builtin_amdgcn_cvt_pkrtz(b.z, b.w);
        *(uint4*)&As[r * E_ + ((c ^ (r & 7)) * 8)] = make_uint4(p0.u, p1.u, p2.u, p3.u);
    }
    // stage Wc (fp32 -> f16) with chunk swizzle
    for (int i = tid; i < E_ * 16; i += 256) {
        int r = i >> 4, c = i & 15;
        const float* s = Wc + (size_t)r * E_ + c * 8;
        float4 a = *(const float4*)s;
        float4 b = *(const float4*)(s + 4);
        H2U p0, p1, p2, p3;
        p0.h = __builtin_amdgcn_cvt_pkrtz(a.x, a.y);
        p1.h = __builtin_amdgcn_cvt_pkrtz(a.z, a.w);
        p2.h = __builtin_amdgcn_cvt_pkrtz(b.x, b.y);
        p3.h = __builtin_amdgcn_cvt_pkrtz(b.z, b.w);
        *(uint4*)&Bs[r * E_ + ((c ^ (r & 7)) * 8)] = make_uint4(p0.u, p1.u, p2.u, p3.u);
    }
    __syncthreads();

    const int rg = wv & 1;                // row-group: rows rg*32 + m
    const int cp = (wv >> 1) * 2;         // col-groups cp, cp+1

    f32x16 acc0 = {}, acc1 = {};
    const f32x16 zz = {};
    (void)zz;
#pragma unroll
    for (int ks = 0; ks < 8; ++ks) {
        int ch = (ks * 2 + hi);
        f16x8 af  = *(const f16x8*)&As[(rg * 32 + l31) * E_ + ((ch ^ (l31 & 7)) * 8)];
        f16x8 bf0 = *(const f16x8*)&Bs[((cp + 0) * 32 + l31) * E_ + ((ch ^ (l31 & 7)) * 8)];
        f16x8 bf1 = *(const f16x8*)&Bs[((cp + 1) * 32 + l31) * E_ + ((ch ^ (l31 & 7)) * 8)];
        acc0 = __builtin_amdgcn_mfma_f32_32x32x16_f16(af, bf0, acc0, 0, 0, 0);
        acc1 = __builtin_amdgcn_mfma_f32_32x32x16_f16(af, bf1, acc1, 0, 0, 0);
    }

    const float b0 = bc[(cp + 0) * 32 + l31];
    const float b1 = bc[(cp + 1) * 32 + l31];
#pragma unroll
    for (int i = 0; i < 16; ++i) {
        int row = (i & 3) + 8 * (i >> 2) + 4 * hi;
        float* orow = io + (size_t)(r0 + rg * 32 + row) * E_;
        orow[(cp + 0) * 32 + l31] = acc0[i] + b0;
        orow[(cp + 1) * 32 + l31] = acc1[i] + b1;
    }
}

extern "C" void kernel_launch(void* const* d_in, const int* in_sizes, int n_in,
                              void* d_out, int out_size, void* d_ws, size_t ws_size,
                              hipStream_t stream) {
    const float* x     = (const float*)d_in[0];   // (4, 2048, 128)
    const float* theta = (const float*)d_in[1];   // (8,)
    const float* Wc    = (const float*)d_in[2];   // (128, 128)
    const float* bc    = (const float*)d_in[3];   // (128,)
    float* out = (float*)d_out;                   // (4, 2048, 128)

    qattn_mfma<<<dim3(S_ / 256, B_ * H_), 512, 0, stream>>>(x, theta, out);
    proj_mfma<<<dim3((B_ * S_) / 64), 256, 0, stream>>>(Wc, bc, out);
}